// Round 11
// baseline (395.247 us; speedup 1.0000x reference)
//
#include <hip/hip_runtime.h>
#include <hip/hip_bf16.h>
#include <math.h>

#define TKN 16384
#define HID 4096
#define NE  256
#define TOPK 8
#define NGRP 8
#define TOPG 4

#define BM 64
#define BK 64
#define NKT (HID / BK)          // 64 K-steps
#define BIMG 16384              // prep'd B image per (cb,kt): 8 frags x [hi 1K][lo 1K]

typedef _Float16 half8 __attribute__((ext_vector_type(8)));
typedef float    f32x4 __attribute__((ext_vector_type(4)));

static __device__ __forceinline__ unsigned pkrtz(float x, float y) {
    auto r = __builtin_amdgcn_cvt_pkrtz(x, y);   // v_cvt_pkrtz_f16_f32
    return __builtin_bit_cast(unsigned, r);
}
static __device__ __forceinline__ float hi_mask(float a) {
    return __uint_as_float(__float_as_uint(a) & 0xFFFFE000u);
}
// split one float4 into hi/lo f16 pairs and write 8B to each plane.
// IDENTICAL value math to all passing rounds -> bit-identical MFMA inputs.
static __device__ __forceinline__ void split_w(const float4 v,
    unsigned char* hiP, unsigned char* loP, int ofs)
{
    const float h0 = hi_mask(v.x), h1 = hi_mask(v.y),
                h2 = hi_mask(v.z), h3 = hi_mask(v.w);
    *(uint2*)(hiP + ofs) = make_uint2(pkrtz(h0, h1), pkrtz(h2, h3));
    *(uint2*)(loP + ofs) = make_uint2(pkrtz(v.x - h0, v.y - h1),
                                      pkrtz(v.z - h2, v.w - h3));
}

// ---- prep: B [256][4096] f32 -> FRAGMENT-ORDERED f16 hi/lo images ----------
// (verbatim rounds 8/9/10 — validated) wave fragment load = base + lane*16.
__global__ __launch_bounds__(256) void prep_b(const float* __restrict__ B,
                                              unsigned char* __restrict__ ws)
{
    const int gid = blockIdx.x * 256 + threadIdx.x;   // 131072
    const int e   = gid >> 9;          // expert 0..255
    const int k0  = (gid & 511) * 8;   // k chunk of 8
    const float* src = B + (size_t)e * HID + k0;
    float v[8];
    #pragma unroll
    for (int i = 0; i < 8; ++i) v[i] = src[i];
    unsigned hw[4], lw[4];
    #pragma unroll
    for (int j = 0; j < 4; ++j) {
        const float x0 = v[2*j], x1 = v[2*j+1];
        const float h0 = hi_mask(x0), h1 = hi_mask(x1);
        hw[j] = pkrtz(h0, h1);
        lw[j] = pkrtz(x0 - h0, x1 - h1);
    }
    const int cb     = e >> 6;
    const int colgrp = (e & 63) >> 4;
    const int lane16 = e & 15;
    const int kt     = k0 >> 6;
    const int kk     = k0 & 63;
    const int wg     = kk >> 5;
    const int kseg   = (kk >> 3) & 3;
    const int f      = colgrp * 2 + wg;
    unsigned char* img = ws + (size_t)(cb * NKT + kt) * BIMG
                            + f * 2048 + (kseg * 16 + lane16) * 16;
    *(uint4*)(img)        = make_uint4(hw[0], hw[1], hw[2], hw[3]);
    *(uint4*)(img + 1024) = make_uint4(lw[0], lw[1], lw[2], lw[3]);
}

// ---- GEMM: logits = A[T,H] @ B[E,H]^T, f16x2 split, 3 MFMA passes ----------
// vmcnt-aware pipeline: per iter t -- issue B(t+1) FIRST, then A(t+3)
// (in-order vmcnt retirement: waiting on B never retires a younger A;
// the split of A(t+1) waits only on a load issued at t-2 = 2-iter cover).
// Relaxed barrier {lgkmcnt(0); s_barrier} keeps loads in flight across it.
// ds_reads precede ds_writes (in-order DS queue -> MFMA's lgkm wait excludes
// the staging writes). A LDS layout/split math/MFMA chain/epilogue verbatim
// r10 (bit-identical logits).
__global__ __launch_bounds__(256, 3) void gemm_mfma(
    const float* __restrict__ A, const unsigned char* __restrict__ Bws,
    float* __restrict__ C)
{
    // [buf][plane hi/lo][64 rows x 128 B]
    __shared__ __align__(16) unsigned char smem[2][2][8192];   // 32 KiB

    const int tid  = threadIdx.x;
    const int lane = tid & 63;
    const int wave = tid >> 6;          // 0..3
    const int wg = wave >> 1;           // split-K half
    const int wc = wave & 1;            // col 32-half

    // XCD-bijective remap: cb-quads (same A panel) adjacent on one XCD
    const int logical = (blockIdx.x & 7) * 128 + (blockIdx.x >> 3);
    const int mb   = logical >> 2;      // 0..255
    const int cb   = logical & 3;       // 0..3
    const int row0 = mb * BM;

    // A staging: thread's 4 chunks = rows i*16 + wave*4 + (lane>>4),
    // raw col floats (lane&15)*4 — each staged load is 1KB lane-contiguous.
    const float* srcp[4];
    int wofs[4];
    #pragma unroll
    for (int i = 0; i < 4; ++i) {
        const int r = i * 16 + wave * 4 + (lane >> 4);
        srcp[i] = A + (size_t)(row0 + r) * HID + (lane & 15) * 4;
        wofs[i] = r * 128 + (((lane & 15) * 8) ^ ((r & 7) << 4));
    }

    // A fragment read addressing (r10-proven: 0 conflicts)
    const int kx    = ((wg * 64) + ((lane >> 4) << 4)) ^ ((lane & 7) << 4);
    const int aRowB = (lane & 15) * 128;

    // B fragment offsets (verbatim r8/r9/r10)
    const unsigned char* bBase = Bws + (size_t)cb * NKT * BIMG;
    const int f0off = ((wc * 2 + 0) * 2 + wg) * 2048 + lane * 16;
    const int f1off = ((wc * 2 + 1) * 2 + wg) * 2048 + lane * 16;

    f32x4 acc[4][2];
    #pragma unroll
    for (int i = 0; i < 4; ++i) { acc[i][0] = (f32x4)0.f; acc[i][1] = (f32x4)0.f; }

    float4 a0[4], a1[4], a2[4], a3[4];   // 4-bank A rotation (3 live)
    half8  bA[4], bB[4];                 // B frag banks

    // prologue: A(0)->a0, A(1)->a1, A(2)->a2, B(0)->bA; split A(0)->buf0
    #pragma unroll
    for (int i = 0; i < 4; ++i) a0[i] = *(const float4*)(srcp[i]);
    #pragma unroll
    for (int i = 0; i < 4; ++i) a1[i] = *(const float4*)(srcp[i] + BK);
    #pragma unroll
    for (int i = 0; i < 4; ++i) a2[i] = *(const float4*)(srcp[i] + 2 * BK);
    bA[0] = *(const half8*)(bBase + f0off);
    bA[1] = *(const half8*)(bBase + f0off + 1024);
    bA[2] = *(const half8*)(bBase + f1off);
    bA[3] = *(const half8*)(bBase + f1off + 1024);
    #pragma unroll
    for (int i = 0; i < 4; ++i)
        split_w(a0[i], &smem[0][0][0], &smem[0][1][0], wofs[i]);
    __syncthreads();

#define PSTEP(T, ASPL, AISS, BCUR, BNXT)                                       \
    {                                                                          \
        const int t_ = (T);                                                    \
        if (t_ + 1 < NKT) {  /* 1. issue B(t+1) (L2) FIRST */                  \
            const unsigned char* bp = bBase + (size_t)(t_ + 1) * BIMG;         \
            BNXT[0] = *(const half8*)(bp + f0off);                             \
            BNXT[1] = *(const half8*)(bp + f0off + 1024);                      \
            BNXT[2] = *(const half8*)(bp + f1off);                             \
            BNXT[3] = *(const half8*)(bp + f1off + 1024);                      \
        }                                                                      \
        __builtin_amdgcn_sched_barrier(0);                                     \
        if (t_ + 3 < NKT) {  /* 2. issue A(t+3) (HBM) AFTER B */               \
            _Pragma("unroll")                                                  \
            for (int i = 0; i < 4; ++i)                                        \
                AISS[i] = *(const float4*)(srcp[i] + (t_ + 3) * BK);           \
        }                                                                      \
        __builtin_amdgcn_sched_barrier(0);                                     \
        /* 3. relaxed barrier: LDS visibility only, NO vmcnt drain */          \
        asm volatile("s_waitcnt lgkmcnt(0)\n\ts_barrier" ::: "memory");        \
        /* 4. ds_read current buffer (before any ds_write) */                  \
        half8 ah[4], al[4];                                                    \
        {                                                                      \
            const unsigned char* rb = &smem[t_ & 1][0][0];                     \
            _Pragma("unroll")                                                  \
            for (int mt = 0; mt < 4; ++mt) {                                   \
                ah[mt] = *(const half8*)(rb + aRowB + mt * 2048 + kx);         \
                al[mt] = *(const half8*)(rb + 8192 + aRowB + mt * 2048 + kx);  \
            }                                                                  \
        }                                                                      \
        /* 5. split A(t+1) (issued t-2) into the non-read buffer */            \
        if (t_ + 1 < NKT) {                                                    \
            unsigned char* wb = &smem[(t_ + 1) & 1][0][0];                     \
            _Pragma("unroll")                                                  \
            for (int i = 0; i < 4; ++i)                                        \
                split_w(ASPL[i], wb, wb + 8192, wofs[i]);                      \
        }                                                                      \
        /* 6. MFMA (chain verbatim r10 -> bit-identical) */                    \
        _Pragma("unroll")                                                      \
        for (int mt = 0; mt < 4; ++mt) {                                       \
            f32x4 c0 = acc[mt][0];                                             \
            c0 = __builtin_amdgcn_mfma_f32_16x16x32_f16(ah[mt], BCUR[0], c0, 0, 0, 0); \
            c0 = __builtin_amdgcn_mfma_f32_16x16x32_f16(ah[mt], BCUR[1], c0, 0, 0, 0); \
            c0 = __builtin_amdgcn_mfma_f32_16x16x32_f16(al[mt], BCUR[0], c0, 0, 0, 0); \
            acc[mt][0] = c0;                                                   \
            f32x4 c1 = acc[mt][1];                                             \
            c1 = __builtin_amdgcn_mfma_f32_16x16x32_f16(ah[mt], BCUR[2], c1, 0, 0, 0); \
            c1 = __builtin_amdgcn_mfma_f32_16x16x32_f16(ah[mt], BCUR[3], c1, 0, 0, 0); \
            c1 = __builtin_amdgcn_mfma_f32_16x16x32_f16(al[mt], BCUR[2], c1, 0, 0, 0); \
            acc[mt][1] = c1;                                                   \
        }                                                                      \
    }

    for (int kt = 0; kt < NKT; kt += 4) {
        PSTEP(kt + 0, a1, a3, bA, bB);
        PSTEP(kt + 1, a2, a0, bB, bA);
        PSTEP(kt + 2, a3, a1, bA, bB);
        PSTEP(kt + 3, a0, a2, bB, bA);
    }
#undef PSTEP

    // epilogue: reduce wg1 into wg0 through LDS (verbatim r10 math), write C
    float* redf = (float*)&smem[0][0][0];            // buf0 (16 KB) scratch
    const int fb = wc * 2048 + lane * 4;             // float index
    if (wg == 1) {
        #pragma unroll
        for (int mt = 0; mt < 4; ++mt)
            #pragma unroll
            for (int nt = 0; nt < 2; ++nt)
                *(f32x4*)&redf[fb + (mt * 2 + nt) * 256] = acc[mt][nt];
    }
    __syncthreads();
    if (wg == 0) {
        #pragma unroll
        for (int mt = 0; mt < 4; ++mt) {
            #pragma unroll
            for (int nt = 0; nt < 2; ++nt) {
                f32x4 o = acc[mt][nt] + *(const f32x4*)&redf[fb + (mt * 2 + nt) * 256];
                const int r0 = row0 + mt * 16 + (lane >> 4) * 4;
                const int cc = cb * 64 + wc * 32 + nt * 16 + (lane & 15);
                #pragma unroll
                for (int r = 0; r < 4; ++r)
                    C[(size_t)(r0 + r) * NE + cc] = o[r];
            }
        }
    }
}

// ---------------- Router: per-token top-k (verified rounds 1-3, 5-10) -------
__global__ __launch_bounds__(256) void router_topk_kernel(
    const float* __restrict__ logits, const float* __restrict__ bias,
    float* __restrict__ out_w, float* __restrict__ out_i)
{
    const int wid  = threadIdx.x >> 6;
    const int lane = threadIdx.x & 63;
    const int token = blockIdx.x * 4 + wid;

    const float* row = logits + (size_t)token * NE;
    const float4 lg = *(const float4*)&row[lane * 4];

    float sig[4], sc[4];
    {
        const float l4[4] = {lg.x, lg.y, lg.z, lg.w};
        #pragma unroll
        for (int j = 0; j < 4; ++j) {
            sig[j] = 1.f / (1.f + expf(-l4[j]));
            sc[j]  = sig[j] + bias[lane * 4 + j];
        }
    }

    float m1 = sc[0], m2 = -INFINITY;
    #pragma unroll
    for (int j = 1; j < 4; ++j) {
        if (sc[j] > m1) { m2 = m1; m1 = sc[j]; }
        else if (sc[j] > m2) { m2 = sc[j]; }
    }
    #pragma unroll
    for (int off = 1; off < 8; off <<= 1) {
        const float o1 = __shfl_xor(m1, off);
        const float o2 = __shfl_xor(m2, off);
        const float lo = fminf(m1, o1);
        m1 = fmaxf(m1, o1);
        m2 = fmaxf(lo, fmaxf(m2, o2));
    }
    const float gscore = m1 + m2;

    const int gmy = lane >> 3;
    int rank = 0;
    #pragma unroll
    for (int g = 0; g < NGRP; ++g) {
        const float gs = __shfl(gscore, g * 8);
        if (gs > gscore || (gs == gscore && g < gmy)) ++rank;
    }
    if (rank >= TOPG) {
        #pragma unroll
        for (int j = 0; j < 4; ++j) sc[j] = -INFINITY;
    }

    float wk[TOPK]; int ik[TOPK];
    float wsum = 0.f;
    #pragma unroll
    for (int k = 0; k < TOPK; ++k) {
        float bv = sc[0]; int bi = lane * 4;
        #pragma unroll
        for (int j = 1; j < 4; ++j)
            if (sc[j] > bv) { bv = sc[j]; bi = lane * 4 + j; }
        #pragma unroll
        for (int off = 1; off < 64; off <<= 1) {
            const float v2 = __shfl_xor(bv, off);
            const int   i2 = __shfl_xor(bi, off);
            if (v2 > bv || (v2 == bv && i2 < bi)) { bv = v2; bi = i2; }
        }
        const int owner = bi >> 2;
        const int j = bi & 3;
        const float sv = (j == 0) ? sig[0] : (j == 1) ? sig[1] : (j == 2) ? sig[2] : sig[3];
        const float w = __shfl(sv, owner);
        wk[k] = w; ik[k] = bi; wsum += w;
        if (lane == owner) {
            if (j == 0) sc[0] = -INFINITY;
            else if (j == 1) sc[1] = -INFINITY;
            else if (j == 2) sc[2] = -INFINITY;
            else sc[3] = -INFINITY;
        }
    }

    if (lane == 0) {
        const float denom = wsum + 1e-20f;
        #pragma unroll
        for (int k = 0; k < TOPK; ++k) {
            out_w[(size_t)token * TOPK + k] = wk[k] / denom;
            out_i[(size_t)token * TOPK + k] = (float)ik[k];
        }
    }
}

extern "C" void kernel_launch(void* const* d_in, const int* in_sizes, int n_in,
                              void* d_out, int out_size, void* d_ws, size_t ws_size,
                              hipStream_t stream) {
    const float* hidden = (const float*)d_in[0];
    const float* weight = (const float*)d_in[1];
    const float* bias   = (const float*)d_in[2];

    float* logits = (float*)d_out;                              // [T, E]
    float* out_w  = logits + (size_t)TKN * NE;                  // [T, 8]
    float* out_i  = out_w + (size_t)TKN * TOPK;                 // [T, 8]

    unsigned char* bpl = (unsigned char*)d_ws;                  // 4 MB B images

    prep_b<<<512, 256, 0, stream>>>(weight, bpl);
    gemm_mfma<<<1024, 256, 0, stream>>>(hidden, bpl, logits);
    router_topk_kernel<<<TKN / 4, 256, 0, stream>>>(logits, bias, out_w, out_i);
}